// Round 5
// baseline (15871.402 us; speedup 1.0000x reference)
//
#include <hip/hip_runtime.h>
#include <stdint.h>

typedef unsigned short u16;
typedef unsigned int   u32;
typedef __attribute__((ext_vector_type(8))) short bf8v;          // 8 x bf16 MFMA frag
typedef __attribute__((ext_vector_type(4))) float f4v;           // MFMA acc frag
typedef __attribute__((ext_vector_type(8))) unsigned short us8v; // 16B bf16 vector

__device__ __forceinline__ float bfs(u16 u){ union { u32 i; float f; } v; v.i = ((u32)u) << 16; return v.f; }
__device__ __forceinline__ u16 f2bf(float f){ union { float f; u32 i; } v; v.f = f; u32 i = v.i; return (u16)((i + 0x7fffu + ((i >> 16) & 1u)) >> 16); }
__device__ __forceinline__ float sigm(float x){ return 1.f / (1.f + __expf(-x)); }
__device__ __forceinline__ float tanh_(float x){ float e = __expf(2.f * x); return 1.f - 2.f / (e + 1.f); }

// ---------------- prep kernels (proven round-4 structure) ----------------

__global__ __launch_bounds__(256) void k_transpose_fm(const float* __restrict__ fm, u16* __restrict__ out, int b_base){
  __shared__ u16 tile[64][65];
  int b = blockIdx.z, hw0 = blockIdx.x * 64, ci0 = blockIdx.y * 64;
  int tid = threadIdx.x;
  int hwl = tid & 63, ci_l = tid >> 6;
  #pragma unroll
  for (int r = 0; r < 16; ++r){
    int ci = ci_l * 16 + r;
    tile[ci][hwl] = f2bf(fm[((size_t)((b_base + b) * 512 + ci0 + ci)) * 256 + hw0 + hwl]);
  }
  __syncthreads();
  int cil = tid & 63, hw_l = tid >> 6;
  #pragma unroll
  for (int r = 0; r < 16; ++r){
    int hw = hw_l * 16 + r;
    out[((size_t)(b * 256 + hw0 + hw)) * 512 + ci0 + cil] = tile[cil][hw];
  }
}

__global__ __launch_bounds__(256) void k_wt_prep(const float* __restrict__ w, u16* __restrict__ wt){
  int idx = blockIdx.x * 256 + threadIdx.x;         // 9*512*512
  int ci = idx & 511, co = (idx >> 9) & 511, dydx = idx >> 18;
  wt[idx] = f2bf(w[((size_t)(co * 512 + ci)) * 9 + dydx]);
}

__global__ __launch_bounds__(256) void k_cvt(const float* __restrict__ src, u16* __restrict__ dst, int n){
  int idx = blockIdx.x * 256 + threadIdx.x;
  if (idx < n) dst[idx] = f2bf(src[idx]);
}
__global__ __launch_bounds__(256) void k_cvt_rw1(const float* __restrict__ src, u16* __restrict__ dst){
  int idx = blockIdx.x * 256 + threadIdx.x;   // 2048*512
  int n = idx >> 9, k = idx & 511;
  dst[idx] = f2bf(src[(size_t)n * 550 + k]);
}
__global__ __launch_bounds__(256) void k_cvt_gen(const float* __restrict__ src, u16* __restrict__ dst){
  int idx = blockIdx.x * 256 + threadIdx.x;   // 48*512
  int n = idx >> 9, k = idx & 511;
  dst[idx] = (n < 38) ? f2bf(src[(size_t)n * 512 + k]) : (u16)0;
}

// Wq[n][j] = sum_k ch2h[n][k] * h2h[k][j]   (one-time 512^3 f32 -> bf16)
__global__ __launch_bounds__(256) void k_wq(const float* __restrict__ w1, const float* __restrict__ hh,
                                            u16* __restrict__ wq){
  int n = blockIdx.x, j = threadIdx.x;
  float a0 = 0.f, a1 = 0.f;
  for (int k = 0; k < 512; ++k){
    float w = w1[n * 512 + k];
    a0 = fmaf(w, hh[k * 512 + j], a0);
    a1 = fmaf(w, hh[k * 512 + j + 256], a1);
  }
  wq[n * 512 + j] = f2bf(a0);
  wq[n * 512 + j + 256] = f2bf(a1);
}

// ---------------- conv3x3 implicit GEMM (unchanged, proven) ----------------
__global__ __launch_bounds__(256) void k_conv(
    const u16* __restrict__ in_t, const u16* __restrict__ Wt,
    const float* __restrict__ cbias, u16* __restrict__ fmh, int b_base)
{
  __shared__ u16 As[128 * 32];
  __shared__ u16 Bs[128 * 32];
  int tid = threadIdx.x;
  int wave = tid >> 6, lane = tid & 63;
  int nb = blockIdx.x & 3, mb = blockIdx.x >> 2;
  int m0 = mb * 128, n0 = nb * 128;
  int bb = m0 >> 8;
  int r = tid >> 1;
  int seg = (tid & 1) * 16;
  int hwl = (mb & 1) * 128 + r;
  int y = hwl >> 5, x = hwl & 31;
  const u16* aBase = in_t + ((size_t)bb * 256) * 512 + seg;
  const u16* bBase = Wt + ((size_t)(n0 + r)) * 512 + seg;
  int lm = lane & 15, quad = lane >> 4;
  int wm = (wave & 1) * 64, wn = (wave >> 1) * 64;
  f4v acc[4][4];
  #pragma unroll
  for (int i = 0; i < 4; ++i)
    #pragma unroll
    for (int j = 0; j < 4; ++j)
      acc[i][j] = (f4v){0.f, 0.f, 0.f, 0.f};

  for (int dydx = 0; dydx < 9; ++dydx){
    int dy = dydx / 3, dx = dydx - dy * 3;
    int yy = y + dy - 1, xx = x + dx - 1;
    bool ok = (yy >= 0) && (yy < 8) && (xx >= 0) && (xx < 32);
    const u16* aRow = aBase + (ptrdiff_t)(yy * 32 + xx) * 512;
    const u16* bRow = bBase + (size_t)dydx * 262144;
    for (int kc = 0; kc < 16; ++kc){
      us8v a0 = (us8v){0,0,0,0,0,0,0,0}, a1 = a0;
      if (ok){
        a0 = *(const us8v*)(aRow + kc * 32);
        a1 = *(const us8v*)(aRow + kc * 32 + 8);
      }
      us8v b0 = *(const us8v*)(bRow + kc * 32);
      us8v b1 = *(const us8v*)(bRow + kc * 32 + 8);
      __syncthreads();
      *(us8v*)&As[r * 32 + seg]     = a0;
      *(us8v*)&As[r * 32 + seg + 8] = a1;
      *(us8v*)&Bs[r * 32 + seg]     = b0;
      *(us8v*)&Bs[r * 32 + seg + 8] = b1;
      __syncthreads();
      bf8v af[4], bfr[4];
      #pragma unroll
      for (int i = 0; i < 4; ++i) af[i]  = *(const bf8v*)&As[(wm + i * 16 + lm) * 32 + quad * 8];
      #pragma unroll
      for (int j = 0; j < 4; ++j) bfr[j] = *(const bf8v*)&Bs[(wn + j * 16 + lm) * 32 + quad * 8];
      #pragma unroll
      for (int i = 0; i < 4; ++i)
        #pragma unroll
        for (int j = 0; j < 4; ++j)
          acc[i][j] = __builtin_amdgcn_mfma_f32_16x16x32_bf16(af[i], bfr[j], acc[i][j], 0, 0, 0);
    }
  }
  #pragma unroll
  for (int j = 0; j < 4; ++j){
    int co = n0 + wn + j * 16 + lm;
    float bv = cbias[co];
    #pragma unroll
    for (int i = 0; i < 4; ++i){
      int mrow = m0 + wm + i * 16 + quad * 4;
      int hw = mrow & 255;
      ushort4 pk;
      pk.x = f2bf(acc[i][j][0] + bv);
      pk.y = f2bf(acc[i][j][1] + bv);
      pk.z = f2bf(acc[i][j][2] + bv);
      pk.w = f2bf(acc[i][j][3] + bv);
      *(ushort4*)&fmh[((size_t)((b_base + bb) * 512 + co)) * 256 + hw] = pk;
    }
  }
}

// ---------------- prologue ----------------

__global__ __launch_bounds__(256) void k_meanH(const float* __restrict__ H, float* __restrict__ outm){
  int idx = blockIdx.x * 256 + threadIdx.x;  // 256*512
  int b = idx >> 9, k = idx & 511;
  float s = 0.f;
  #pragma unroll
  for (int t = 0; t < 26; ++t) s += H[((size_t)(b * 26 + t)) * 512 + k];
  outm[idx] = s * (1.f / 26.f);
}

// out[256][512] = A @ W^T (+ bias)  (all f32, one-off)
__global__ __launch_bounds__(256) void k_pgemm(const float* __restrict__ A, const float* __restrict__ W,
                                               const float* __restrict__ bias, float* __restrict__ out){
  __shared__ float As[32][33];
  __shared__ float Ws[64][33];
  int tid = threadIdx.x;
  int n0 = blockIdx.x * 64, m0 = blockIdx.y * 32;
  float acc[2][4] = {{0.f,0.f,0.f,0.f},{0.f,0.f,0.f,0.f}};
  int ml = (tid >> 4) * 2, nl = (tid & 15) * 4;
  int sm = tid >> 3, sk = (tid & 7) * 4;
  int wn = tid >> 2, wk = (tid & 3) * 8;
  for (int k0 = 0; k0 < 512; k0 += 32){
    __syncthreads();
    float4 av = *(const float4*)&A[(size_t)(m0 + sm) * 512 + k0 + sk];
    As[sm][sk] = av.x; As[sm][sk+1] = av.y; As[sm][sk+2] = av.z; As[sm][sk+3] = av.w;
    const float* wp = W + (size_t)(n0 + wn) * 512 + k0 + wk;
    #pragma unroll
    for (int u2 = 0; u2 < 8; ++u2) Ws[wn][wk + u2] = wp[u2];
    __syncthreads();
    #pragma unroll
    for (int k = 0; k < 32; ++k){
      float a0 = As[ml][k], a1 = As[ml+1][k];
      float w0 = Ws[nl][k], w1 = Ws[nl+1][k], w2 = Ws[nl+2][k], w3 = Ws[nl+3][k];
      acc[0][0] = fmaf(a0,w0,acc[0][0]); acc[0][1] = fmaf(a0,w1,acc[0][1]);
      acc[0][2] = fmaf(a0,w2,acc[0][2]); acc[0][3] = fmaf(a0,w3,acc[0][3]);
      acc[1][0] = fmaf(a1,w0,acc[1][0]); acc[1][1] = fmaf(a1,w1,acc[1][1]);
      acc[1][2] = fmaf(a1,w2,acc[1][2]); acc[1][3] = fmaf(a1,w3,acc[1][3]);
    }
  }
  #pragma unroll
  for (int i = 0; i < 2; ++i)
    #pragma unroll
    for (int j = 0; j < 4; ++j){
      int n = n0 + nl + j;
      float v = acc[i][j] + (bias ? bias[n] : 0.f);
      out[(size_t)(m0 + ml + i) * 512 + n] = v;
    }
}

__global__ __launch_bounds__(256) void k_init(const float* __restrict__ hh, const float* __restrict__ hc,
                                              u16* h1, float* c1, u16* h2, float* c2){
  int idx = blockIdx.x * 256 + threadIdx.x;  // 131072
  float h0 = 0.5f * (hh[idx] + hh[idx + 131072]);
  float c0 = 0.5f * (hc[idx] + hc[idx + 131072]);
  u16 hb = f2bf(h0);
  h1[idx] = hb; h2[idx] = hb; c1[idx] = c0; c2[idx] = c0;
}

// ---------------- persistent recurrence kernel ----------------

#define NBLK 128

__device__ __forceinline__ void gbar(u32* bcnt, u32* bgen, u32 target){
  __threadfence();
  __syncthreads();
  if (threadIdx.x == 0){
    u32 t = __hip_atomic_fetch_add(bcnt, 1u, __ATOMIC_ACQ_REL, __HIP_MEMORY_SCOPE_AGENT);
    if (t == (u32)NBLK - 1){
      __hip_atomic_store(bcnt, 0u, __ATOMIC_RELAXED, __HIP_MEMORY_SCOPE_AGENT);
      __hip_atomic_store(bgen, target, __ATOMIC_RELEASE, __HIP_MEMORY_SCOPE_AGENT);
    } else {
      long spins = 0;
      while (__hip_atomic_load(bgen, __ATOMIC_ACQUIRE, __HIP_MEMORY_SCOPE_AGENT) < target){
        if (++spins > (1L << 28)) break;   // bail (wrong-but-terminating)
        __builtin_amdgcn_s_sleep(2);
      }
    }
  }
  __syncthreads();
}

// 128x128-tile GEMM phase: OUT = A1@W1^T (+A2@W2^T) + b1 + b2 + C0 + onehot. 16 waves/tile.
__device__ __forceinline__ void gemm_phase(
    const u16* __restrict__ A1, const u16* __restrict__ W1,
    const u16* __restrict__ A2, const u16* __restrict__ W2,
    const float* __restrict__ b1f, const float* __restrict__ b2f,
    const float* __restrict__ C0, const float* __restrict__ Woh,
    const int* __restrict__ txt, int t,
    void* __restrict__ out, int obf16, int N, int ntn,
    u16* As, u16* Bs)
{
  int tid = threadIdx.x;
  int wave = tid >> 6, lane = tid & 63;
  int lm = lane & 15, quad = lane >> 4;
  int wm = (wave >> 2) * 32, wn = (wave & 3) * 32;
  int sr = (tid & 511) >> 2;           // staging row 0..127
  int sk = (tid & 3) * 8;              // k elem offset
  bool stA = tid < 512;
  int ntasks = 2 * ntn;                // M=256 fixed
  for (int task = blockIdx.x; task < ntasks; task += NBLK){
    int m0 = (task / ntn) * 128, n0 = (task % ntn) * 128;
    f4v acc[2][2];
    #pragma unroll
    for (int i = 0; i < 2; ++i)
      #pragma unroll
      for (int j = 0; j < 2; ++j)
        acc[i][j] = (f4v){0.f, 0.f, 0.f, 0.f};
    #pragma unroll 1
    for (int pass = 0; pass < 2; ++pass){
      const u16* A = pass ? A2 : A1;
      const u16* W = pass ? W2 : W1;
      if (!A) break;
      const u16* gp = stA ? (A + (size_t)(m0 + sr) * 512 + sk)
                          : (W + (size_t)(n0 + sr) * 512 + sk);
      u16* lp = stA ? (As + sr * 32 + sk) : (Bs + sr * 32 + sk);
      for (int kc = 0; kc < 16; ++kc){
        us8v v = *(const us8v*)(gp + kc * 32);
        __syncthreads();
        *(us8v*)lp = v;
        __syncthreads();
        bf8v a0 = *(const bf8v*)&As[(wm + lm) * 32 + quad * 8];
        bf8v a1 = *(const bf8v*)&As[(wm + 16 + lm) * 32 + quad * 8];
        bf8v b0 = *(const bf8v*)&Bs[(wn + lm) * 32 + quad * 8];
        bf8v b1 = *(const bf8v*)&Bs[(wn + 16 + lm) * 32 + quad * 8];
        acc[0][0] = __builtin_amdgcn_mfma_f32_16x16x32_bf16(a0, b0, acc[0][0], 0, 0, 0);
        acc[0][1] = __builtin_amdgcn_mfma_f32_16x16x32_bf16(a0, b1, acc[0][1], 0, 0, 0);
        acc[1][0] = __builtin_amdgcn_mfma_f32_16x16x32_bf16(a1, b0, acc[1][0], 0, 0, 0);
        acc[1][1] = __builtin_amdgcn_mfma_f32_16x16x32_bf16(a1, b1, acc[1][1], 0, 0, 0);
      }
    }
    #pragma unroll
    for (int j = 0; j < 2; ++j){
      int n = n0 + wn + j * 16 + lm;
      float badd = 0.f;
      if (b1f) badd += b1f[n];
      if (b2f) badd += b2f[n];
      #pragma unroll
      for (int i = 0; i < 2; ++i){
        int mr = m0 + wm + i * 16 + quad * 4;
        #pragma unroll
        for (int reg = 0; reg < 4; ++reg){
          int m = mr + reg;
          float v = acc[i][j][reg] + badd;
          if (C0)  v += C0[(size_t)m * N + n];
          if (Woh) v += Woh[(size_t)n * 550 + 512 + txt[m * 26 + t]];
          if (obf16) ((u16*)out)[(size_t)m * N + n] = f2bf(v);
          else       ((float*)out)[(size_t)m * N + n] = v;
        }
      }
    }
  }
}

__device__ __forceinline__ void lstm_phase(const float* __restrict__ g, float* __restrict__ c,
                                           u16* __restrict__ h, u16* __restrict__ hid, int t){
  int idx = blockIdx.x * 1024 + threadIdx.x;   // 131072
  int b = idx >> 9, j = idx & 511;
  const float* gb = g + (size_t)b * 2048;
  float iv = sigm(gb[j]);
  float fv = sigm(gb[512 + j]);
  float gv = tanh_(gb[1024 + j]);
  float ov = sigm(gb[1536 + j]);
  float cc = fv * c[idx] + iv * gv;
  float hh = ov * tanh_(cc);
  u16 hb = f2bf(hh);
  c[idx] = cc; h[idx] = hb;
  if (hid) hid[((size_t)(b * 26 + t)) * 512 + j] = hb;
}

__device__ __forceinline__ void attn_phase(const u16* __restrict__ fmh, const u16* __restrict__ qb,
    const float* __restrict__ sw, const float* __restrict__ sb, u16* __restrict__ ctxb,
    float* qs, float* wss, float* pe, float* red, float* alpha)
{
  int tid = threadIdx.x;
  for (int bs = 0; bs < 2; ++bs){
    int b = blockIdx.x + bs * NBLK;
    if (tid < 512){ qs[tid] = bfs(qb[b * 512 + tid]); wss[tid] = sw[tid]; }
    __syncthreads();
    const u16* fb = fmh + (size_t)b * 131072;
    int part = tid >> 8, hw = tid & 255;
    const u16* col = fb + (size_t)(part * 128) * 256 + hw;
    int cb0 = part * 128;
    float e0 = 0.f, e1 = 0.f, e2 = 0.f, e3 = 0.f;
    for (int c = 0; c < 128; c += 4){
      e0 = fmaf(tanh_(bfs(col[(c+0)*256]) + qs[cb0+c+0]), wss[cb0+c+0], e0);
      e1 = fmaf(tanh_(bfs(col[(c+1)*256]) + qs[cb0+c+1]), wss[cb0+c+1], e1);
      e2 = fmaf(tanh_(bfs(col[(c+2)*256]) + qs[cb0+c+2]), wss[cb0+c+2], e2);
      e3 = fmaf(tanh_(bfs(col[(c+3)*256]) + qs[cb0+c+3]), wss[cb0+c+3], e3);
    }
    pe[part * 256 + hw] = (e0 + e1) + (e2 + e3);
    __syncthreads();
    float e = 0.f;
    if (tid < 256){
      e = pe[tid] + pe[256 + tid] + pe[512 + tid] + pe[768 + tid] + sb[0];
      red[tid] = e;
    }
    __syncthreads();
    for (int off = 128; off > 0; off >>= 1){
      if (tid < off) red[tid] = fmaxf(red[tid], red[tid + off]);
      __syncthreads();
    }
    float mx = red[0];
    __syncthreads();
    float ex = 0.f;
    if (tid < 256){ ex = __expf(e - mx); red[tid] = ex; }
    __syncthreads();
    for (int off = 128; off > 0; off >>= 1){
      if (tid < off) red[tid] += red[tid + off];
      __syncthreads();
    }
    if (tid < 256) alpha[tid] = ex / red[0];
    __syncthreads();
    // context: wave w -> channels c = w*32 .. +32
    int wave = tid >> 6, lane = tid & 63;
    float a4[4];
    #pragma unroll
    for (int i2 = 0; i2 < 4; ++i2) a4[i2] = alpha[lane * 4 + i2];
    for (int cc = 0; cc < 32; ++cc){
      int c = wave * 32 + cc;
      ushort4 v = *(const ushort4*)(fb + (size_t)c * 256 + lane * 4);
      float p = a4[0]*bfs(v.x) + a4[1]*bfs(v.y) + a4[2]*bfs(v.z) + a4[3]*bfs(v.w);
      #pragma unroll
      for (int off = 32; off > 0; off >>= 1) p += __shfl_xor(p, off);
      if (lane == 0) ctxb[(size_t)b * 512 + c] = f2bf(p);
    }
    __syncthreads();
  }
}

__global__ __launch_bounds__(1024, 4) void k_persist(
    const u16* __restrict__ fmh,
    const u16* __restrict__ WqB, const float* __restrict__ qbase, u16* __restrict__ qb,
    const float* __restrict__ score_w, const float* __restrict__ score_b, u16* __restrict__ ctxb,
    const u16* __restrict__ r1wB, const u16* __restrict__ r1hB,
    const float* __restrict__ r1_bih, const float* __restrict__ r1_bhh,
    const float* __restrict__ r1_wih, const int* __restrict__ text,
    float* __restrict__ gbuf, float* __restrict__ c1, u16* __restrict__ h1,
    const u16* __restrict__ hlinB, const float* __restrict__ hlin_b, u16* __restrict__ curb,
    const u16* __restrict__ r2wB, const u16* __restrict__ r2hB,
    const float* __restrict__ r2_bih, const float* __restrict__ r2_bhh,
    float* __restrict__ c2, u16* __restrict__ h2, u16* __restrict__ hid,
    u32* __restrict__ bar)
{
  __shared__ u16 As[4096], Bs[4096];
  __shared__ float qs[512], wss[512], pe[1024], red[256], alpha[256];
  u32* bcnt = bar; u32* bgen = bar + 1;
  u32 gen = 0;
  for (int t = 0; t < 26; ++t){
    // P1: q = h2 @ Wq^T + qbase
    gemm_phase(h2, WqB, nullptr, nullptr, nullptr, nullptr, qbase, nullptr, nullptr, 0,
               qb, 1, 512, 4, As, Bs);
    gbar(bcnt, bgen, ++gen);
    // P2: attention (block-local per batch)
    attn_phase(fmh, qb, score_w, score_b, ctxb, qs, wss, pe, red, alpha);
    gbar(bcnt, bgen, ++gen);
    // P3: gates1 = ctx@r1w^T + h1@r1h^T + b_ih + b_hh + onehot
    gemm_phase(ctxb, r1wB, h1, r1hB, r1_bih, r1_bhh, nullptr, r1_wih, text, t,
               gbuf, 0, 2048, 16, As, Bs);
    gbar(bcnt, bgen, ++gen);
    // P4: lstm1 -> h1, c1
    lstm_phase(gbuf, c1, h1, nullptr, 0);
    gbar(bcnt, bgen, ++gen);
    // P5: cur = h1 @ hlin^T + hlin_b
    gemm_phase(h1, hlinB, nullptr, nullptr, hlin_b, nullptr, nullptr, nullptr, nullptr, 0,
               curb, 1, 512, 4, As, Bs);
    gbar(bcnt, bgen, ++gen);
    // P6: gates2 = cur@r2w^T + h2@r2h^T + b_ih + b_bhh
    gemm_phase(curb, r2wB, h2, r2hB, r2_bih, r2_bhh, nullptr, nullptr, nullptr, 0,
               gbuf, 0, 2048, 16, As, Bs);
    gbar(bcnt, bgen, ++gen);
    // P7: lstm2 -> h2, c2, hid[:,t,:]
    lstm_phase(gbuf, c2, h2, hid, t);
    gbar(bcnt, bgen, ++gen);
  }
}

// final projection: out[6656][38] = hid @ genw^T + gen_b
__global__ __launch_bounds__(256) void k_gen(const u16* __restrict__ hid,
    const u16* __restrict__ genw, const float* __restrict__ gb, float* __restrict__ out)
{
  __shared__ u16 As[128 * 32];
  __shared__ u16 Bs[48 * 32];
  int tid = threadIdx.x;
  int wave = tid >> 6, lane = tid & 63;
  int m0 = blockIdx.x * 128;
  int r = tid >> 1, seg = (tid & 1) * 16;
  int lm = lane & 15, quad = lane >> 4;
  int mw = wave * 32;
  f4v acc[2][3];
  #pragma unroll
  for (int i = 0; i < 2; ++i)
    #pragma unroll
    for (int j = 0; j < 3; ++j)
      acc[i][j] = (f4v){0.f, 0.f, 0.f, 0.f};
  const u16* aRow = hid + (size_t)(m0 + r) * 512 + seg;
  const u16* bRow = genw + (size_t)r * 512 + seg;
  for (int kc = 0; kc < 16; ++kc){
    us8v a0 = *(const us8v*)(aRow + kc * 32);
    us8v a1 = *(const us8v*)(aRow + kc * 32 + 8);
    us8v b0, b1;
    if (tid < 96){
      b0 = *(const us8v*)(bRow + kc * 32);
      b1 = *(const us8v*)(bRow + kc * 32 + 8);
    }
    __syncthreads();
    *(us8v*)&As[r * 32 + seg]     = a0;
    *(us8v*)&As[r * 32 + seg + 8] = a1;
    if (tid < 96){
      *(us8v*)&Bs[r * 32 + seg]     = b0;
      *(us8v*)&Bs[r * 32 + seg + 8] = b1;
    }
    __syncthreads();
    bf8v af[2], bfr[3];
    #pragma unroll
    for (int i = 0; i < 2; ++i) af[i]  = *(const bf8v*)&As[(mw + i * 16 + lm) * 32 + quad * 8];
    #pragma unroll
    for (int j = 0; j < 3; ++j) bfr[j] = *(const bf8v*)&Bs[(j * 16 + lm) * 32 + quad * 8];
    #pragma unroll
    for (int i = 0; i < 2; ++i)
      #pragma unroll
      for (int j = 0; j < 3; ++j)
        acc[i][j] = __builtin_amdgcn_mfma_f32_16x16x32_bf16(af[i], bfr[j], acc[i][j], 0, 0, 0);
  }
  #pragma unroll
  for (int j = 0; j < 3; ++j){
    int n = j * 16 + lm;
    if (n >= 38) continue;
    float bv = gb[n];
    #pragma unroll
    for (int i = 0; i < 2; ++i){
      int mb = m0 + mw + i * 16 + quad * 4;
      #pragma unroll
      for (int reg = 0; reg < 4; ++reg)
        out[(size_t)(mb + reg) * 38 + n] = acc[i][j][reg] + bv;
    }
  }
}

extern "C" void kernel_launch(void* const* d_in, const int* in_sizes, int n_in,
                              void* d_out, int out_size, void* d_ws, size_t ws_size,
                              hipStream_t stream)
{
  (void)in_sizes; (void)n_in; (void)out_size; (void)ws_size;
  const float* fm      = (const float*)d_in[0];
  const float* batchH  = (const float*)d_in[1];
  const float* hh      = (const float*)d_in[2];
  const float* hc      = (const float*)d_in[3];
  const int*   text    = (const int*)d_in[4];
  const float* i2h_w   = (const float*)d_in[5];
  const float* h2h_w   = (const float*)d_in[6];
  const float* h2h_b   = (const float*)d_in[7];
  const float* cm2h_w  = (const float*)d_in[8];
  const float* cm2h_b  = (const float*)d_in[9];
  const float* ch2h_w  = (const float*)d_in[10];
  const float* ch2h_b  = (const float*)d_in[11];
  const float* score_w = (const float*)d_in[12];
  const float* score_b = (const float*)d_in[13];
  const float* r1_wih  = (const float*)d_in[14];
  const float* r1_whh  = (const float*)d_in[15];
  const float* r1_bih  = (const float*)d_in[16];
  const float* r1_bhh  = (const float*)d_in[17];
  const float* hlin_w  = (const float*)d_in[18];
  const float* hlin_b  = (const float*)d_in[19];
  const float* r2_wih  = (const float*)d_in[20];
  const float* r2_whh  = (const float*)d_in[21];
  const float* r2_bih  = (const float*)d_in[22];
  const float* r2_bhh  = (const float*)d_in[23];
  const float* gen_w   = (const float*)d_in[24];
  const float* gen_b   = (const float*)d_in[25];

  // ---- workspace (88,604,672 B total; proven budget) ----
  char* ws = (char*)d_ws;
  u16* fmh = (u16*)(ws + 0);                 // 67,108,864 B (b,co,hw) bf16
  char* R  = ws + 67108864;                  // 21,495,808 B dual-phase region
  // conv phase overlay:
  u16* Wt    = (u16*)(R + 0);                // 4,718,592
  u16* chunk = (u16*)(R + 4718592);          // 16,777,216
  // post-conv overlay:
  u16* r1wB  = (u16*)(R + 0);                // 2,097,152
  u16* r1hB  = (u16*)(R + 2097152);          // 2,097,152
  u16* r2wB  = (u16*)(R + 4194304);          // 2,097,152
  u16* r2hB  = (u16*)(R + 6291456);          // 2,097,152
  u16* hlinB = (u16*)(R + 8388608);          //   524,288
  u16* WqB   = (u16*)(R + 8912896);          //   524,288
  float* qbase = (float*)(R + 9437184);      //   524,288
  u16* qb    = (u16*)(R + 9961472);          //   262,144
  u16* ctxb  = (u16*)(R + 10223616);         //   262,144
  u16* curb  = (u16*)(R + 10485760);         //   262,144
  u16* h1    = (u16*)(R + 10747904);         //   262,144
  u16* h2    = (u16*)(R + 11010048);         //   262,144
  float* c1  = (float*)(R + 11272192);       //   524,288
  float* c2  = (float*)(R + 11796480);       //   524,288
  float* gbuf = (float*)(R + 12320768);      // 2,097,152 (gates f32)
  float* bh_mean = (float*)(R + 12320768);   //   524,288 (prologue overlay in gbuf)
  float* t1      = (float*)(R + 12845056);   //   524,288 (prologue overlay in gbuf)
  u16* genw  = (u16*)(R + 14417920);         //    49,152
  u32* bar   = (u32*)(R + 14467072);         //       256
  u16* hid   = (u16*)(R + 14680064);         // 6,815,744 -> ends exactly at 21,495,808

  // ---- conv phase ----
  k_wt_prep<<<9216, 256, 0, stream>>>(cm2h_w, Wt);
  for (int rb = 0; rb < 4; ++rb){
    k_transpose_fm<<<dim3(4, 8, 64), 256, 0, stream>>>(fm, chunk, rb * 64);
    k_conv<<<512, 256, 0, stream>>>(chunk, Wt, cm2h_b, fmh, rb * 64);
  }
  // ---- weight converts (overwrite conv staging) ----
  k_cvt_rw1<<<4096, 256, 0, stream>>>(r1_wih, r1wB);
  k_cvt<<<4096, 256, 0, stream>>>(r1_whh, r1hB, 1048576);
  k_cvt<<<4096, 256, 0, stream>>>(r2_wih, r2wB, 1048576);
  k_cvt<<<4096, 256, 0, stream>>>(r2_whh, r2hB, 1048576);
  k_cvt<<<1024, 256, 0, stream>>>(hlin_w, hlinB, 262144);
  k_cvt_gen<<<96, 256, 0, stream>>>(gen_w, genw);
  k_wq<<<512, 256, 0, stream>>>(ch2h_w, h2h_w, WqB);
  // ---- prologue: qbase = (bh_proj + h2h_b) @ ch2h^T + ch2h_b ----
  k_meanH<<<512, 256, 0, stream>>>(batchH, bh_mean);
  k_pgemm<<<dim3(8, 8), 256, 0, stream>>>(bh_mean, i2h_w, h2h_b, t1);
  k_pgemm<<<dim3(8, 8), 256, 0, stream>>>(t1, ch2h_w, ch2h_b, qbase);
  k_init<<<512, 256, 0, stream>>>(hh, hc, h1, c1, h2, c2);
  hipMemsetAsync(bar, 0, 256, stream);
  // ---- persistent 26-step recurrence ----
  k_persist<<<NBLK, 1024, 0, stream>>>(fmh, WqB, qbase, qb, score_w, score_b, ctxb,
      r1wB, r1hB, r1_bih, r1_bhh, r1_wih, text, gbuf, c1, h1,
      hlinB, hlin_b, curb, r2wB, r2hB, r2_bih, r2_bhh, c2, h2, hid, bar);
  // ---- final projection ----
  k_gen<<<52, 256, 0, stream>>>(hid, genw, gen_b, (float*)d_out);
}